// Round 7
// baseline (430.963 us; speedup 1.0000x reference)
//
#include <hip/hip_runtime.h>

#define BN_EPS 1e-5f

static constexpr int D_IN = 128;

using u16 = unsigned short;
using f32x4  = __attribute__((ext_vector_type(4))) float;
using bf16x8 = __attribute__((ext_vector_type(8))) __bf16;

union FragU { uint4 u; bf16x8 v; };

__device__ __forceinline__ u16 f2bf(float f) {
  unsigned int u = __float_as_uint(f);
  u += 0x7FFFu + ((u >> 16) & 1u);   // RNE
  return (u16)(u >> 16);
}
__device__ __forceinline__ float bf2f(u16 h) {
  return __uint_as_float(((unsigned int)h) << 16);
}

// ---------------- graph preprocessing (int32 edge_index per harness rule) -----

__global__ __launch_bounds__(256) void count_kernel(const int* __restrict__ dst, int E,
                                                    int* __restrict__ cnt) {
  int e = blockIdx.x * 256 + threadIdx.x;
  if (e < E) atomicAdd(&cnt[dst[e]], 1);
}

// block sums for scan + dinv = rsqrt(deg+1) fused
__global__ __launch_bounds__(1024) void scan_sum_kernel(const int* __restrict__ cnt, int n,
                                                        int* __restrict__ bsum,
                                                        float* __restrict__ dinv) {
  __shared__ int sdata[1024];
  int i = blockIdx.x * 1024 + threadIdx.x;
  int v = (i < n) ? cnt[i] : 0;
  if (i < n) dinv[i] = rsqrtf((float)v + 1.0f);  // +1: self loop
  sdata[threadIdx.x] = v;
  __syncthreads();
  for (int s = 512; s > 0; s >>= 1) {
    if (threadIdx.x < s) sdata[threadIdx.x] += sdata[threadIdx.x + s];
    __syncthreads();
  }
  if (threadIdx.x == 0) bsum[blockIdx.x] = sdata[0];
}

// exclusive scan; per-block boff computed in-kernel from bsum (<=49 adds)
__global__ __launch_bounds__(1024) void scan_final_kernel(const int* __restrict__ cnt, int n,
                                                          const int* __restrict__ bsum,
                                                          int* __restrict__ rowptr) {
  __shared__ int wt[16];
  __shared__ int sboff;
  int i = blockIdx.x * 1024 + threadIdx.x;
  int lane = threadIdx.x & 63, w = threadIdx.x >> 6;
  int v = (i < n) ? cnt[i] : 0;
  int x = v;
  #pragma unroll
  for (int d = 1; d < 64; d <<= 1) {
    int t = __shfl_up(x, d, 64);
    if (lane >= d) x += t;
  }
  if (lane == 63) wt[w] = x;
  __syncthreads();
  if (threadIdx.x == 0) {
    int run = 0;
    #pragma unroll
    for (int k = 0; k < 16; ++k) { int t = wt[k]; wt[k] = run; run += t; }
    int bo = 0;
    for (int b = 0; b < blockIdx.x; ++b) bo += bsum[b];
    sboff = bo;
  }
  __syncthreads();
  if (i < n) {
    rowptr[i] = x - v + wt[w] + sboff;
    if (i == n - 1) rowptr[n] = x + wt[w] + sboff;  // total = E
  }
}

__global__ __launch_bounds__(256) void fill_kernel(const int* __restrict__ src,
                                                   const int* __restrict__ dst, int E,
                                                   const int* __restrict__ rowptr,
                                                   int* __restrict__ cursor, int* __restrict__ col) {
  int e = blockIdx.x * 256 + threadIdx.x;
  if (e < E) {
    int d = dst[e];
    int p = atomicAdd(&cursor[d], 1);
    col[rowptr[d] + p] = src[e];
  }
}

// -------- fused prep: zero cnt/cursor, x->bf16, W0/W1/W2 -> transposed bf16 ---

__global__ __launch_bounds__(256) void prep_kernel(int* __restrict__ zbuf, int nz, int BZ,
                                                   const float* __restrict__ x, u16* __restrict__ x_bf,
                                                   const float* __restrict__ W0, u16* __restrict__ Wt0,
                                                   const float* __restrict__ W1, u16* __restrict__ Wt1,
                                                   const float* __restrict__ W2, u16* __restrict__ Wt2,
                                                   int N, int BX) {
  int b = blockIdx.x, tid = threadIdx.x;
  if (b < BZ) {
    int i = b * 256 + tid;
    if (i < nz) zbuf[i] = 0;
  } else if (b < BZ + BX) {
    int i = (b - BZ) * 256 + tid;
    if (i < N * 32) {
      float4 v = ((const float4*)x)[i];
      u16 o[4] = { f2bf(v.x), f2bf(v.y), f2bf(v.z), f2bf(v.w) };
      ((uint2*)x_bf)[i] = *(uint2*)o;
    }
  } else if (b < BZ + BX + 128) {       // W0 [128][256] -> Wt0 [256][128]
    int idx = (b - BZ - BX) * 256 + tid;
    int k = idx >> 8, nc = idx & 255;
    Wt0[nc * 128 + k] = f2bf(W0[idx]);
  } else if (b < BZ + BX + 384) {       // W1 [256][256] -> Wt1 [256][256]
    int idx = (b - BZ - BX - 128) * 256 + tid;
    int k = idx >> 8, nc = idx & 255;
    Wt1[nc * 256 + k] = f2bf(W1[idx]);
  } else {                              // W2 [256][128] -> Wt2 [128][256]
    int idx = (b - BZ - BX - 384) * 256 + tid;
    int k = idx >> 7, nc = idx & 127;
    Wt2[nc * 256 + k] = f2bf(W2[idx]);
  }
}

// ---------------- aggregation over bf16 features ----------------
// out[i] = dinv[i]*(sum_j dinv[j]*in[j] + dinv[i]*in[i]) (+bias)(+x fp32 if FINAL)

template<int F, bool BIAS, bool FINAL>
__global__ __launch_bounds__(256) void agg_bf16(const u16* __restrict__ in,
                                                const int* __restrict__ rowptr,
                                                const int* __restrict__ col,
                                                const float* __restrict__ dinv,
                                                const float* __restrict__ bias,
                                                const float* __restrict__ xres,
                                                void* __restrict__ outv, int n) {
  constexpr int V = F / 64;  // bf16 elems per lane (2 or 4)
  int node = blockIdx.x * 4 + (threadIdx.x >> 6);
  if (node >= n) return;
  int lane = threadIdx.x & 63;
  const int off = lane * V;
  const size_t rowbase = (size_t)node * F + off;

  float di = dinv[node];
  float acc[V];
  {
    u16 t[V];
    if constexpr (V == 4) *(uint2*)t = *(const uint2*)(in + rowbase);
    else                  *(unsigned int*)t = *(const unsigned int*)(in + rowbase);
    #pragma unroll
    for (int j = 0; j < V; ++j) acc[j] = di * bf2f(t[j]);
  }

  int e   = __builtin_amdgcn_readfirstlane(rowptr[node]);
  int end = __builtin_amdgcn_readfirstlane(rowptr[node + 1]);
  for (; e + 4 <= end; e += 4) {
    int s0 = col[e], s1 = col[e + 1], s2 = col[e + 2], s3 = col[e + 3];
    float w0 = dinv[s0], w1 = dinv[s1], w2 = dinv[s2], w3 = dinv[s3];
    u16 t0[V], t1[V], t2[V], t3[V];
    if constexpr (V == 4) {
      *(uint2*)t0 = *(const uint2*)(in + (size_t)s0 * F + off);
      *(uint2*)t1 = *(const uint2*)(in + (size_t)s1 * F + off);
      *(uint2*)t2 = *(const uint2*)(in + (size_t)s2 * F + off);
      *(uint2*)t3 = *(const uint2*)(in + (size_t)s3 * F + off);
    } else {
      *(unsigned int*)t0 = *(const unsigned int*)(in + (size_t)s0 * F + off);
      *(unsigned int*)t1 = *(const unsigned int*)(in + (size_t)s1 * F + off);
      *(unsigned int*)t2 = *(const unsigned int*)(in + (size_t)s2 * F + off);
      *(unsigned int*)t3 = *(const unsigned int*)(in + (size_t)s3 * F + off);
    }
    #pragma unroll
    for (int j = 0; j < V; ++j) acc[j] = fmaf(w0, bf2f(t0[j]), acc[j]);
    #pragma unroll
    for (int j = 0; j < V; ++j) acc[j] = fmaf(w1, bf2f(t1[j]), acc[j]);
    #pragma unroll
    for (int j = 0; j < V; ++j) acc[j] = fmaf(w2, bf2f(t2[j]), acc[j]);
    #pragma unroll
    for (int j = 0; j < V; ++j) acc[j] = fmaf(w3, bf2f(t3[j]), acc[j]);
  }
  for (; e < end; ++e) {
    int s0 = col[e];
    float w0 = dinv[s0];
    u16 t0[V];
    if constexpr (V == 4) *(uint2*)t0 = *(const uint2*)(in + (size_t)s0 * F + off);
    else                  *(unsigned int*)t0 = *(const unsigned int*)(in + (size_t)s0 * F + off);
    #pragma unroll
    for (int j = 0; j < V; ++j) acc[j] = fmaf(w0, bf2f(t0[j]), acc[j]);
  }

  #pragma unroll
  for (int j = 0; j < V; ++j) acc[j] *= di;
  if constexpr (BIAS) {
    #pragma unroll
    for (int j = 0; j < V; ++j) acc[j] += bias[off + j];
  }
  if constexpr (FINAL) {
    float* out = (float*)outv;
    float xr[V];
    if constexpr (V == 2) *(float2*)xr = *(const float2*)(xres + rowbase);
    else                  *(float4*)xr = *(const float4*)(xres + rowbase);
    #pragma unroll
    for (int j = 0; j < V; ++j) acc[j] += xr[j];
    if constexpr (V == 2) *(float2*)(out + rowbase) = *(float2*)acc;
    else                  *(float4*)(out + rowbase) = *(float4*)acc;
  } else {
    u16* out = (u16*)outv;
    u16 o[V];
    #pragma unroll
    for (int j = 0; j < V; ++j) o[j] = f2bf(acc[j]);
    if constexpr (V == 4) *(uint2*)(out + rowbase) = *(uint2*)o;
    else                  *(unsigned int*)(out + rowbase) = *(unsigned int*)o;
  }
}

// ------- streaming MFMA GEMM: C[M,NN] = A[M,K] @ Wt[NN,K]^T (+bias) ----------
// B (one 128-col block of Wt) lives entirely in LDS (<=64KB), loaded once via
// global_load_lds with pre-swizzled source chunks (involution c^(r&7) on 16B
// chunks, linear LDS dest). ONE barrier; then each wave independently streams
// 64-row A chunks. No barriers in the main loop.
// STATS: per-block BN partials (padded rows masked) via shfl + LDS atomics.
// APPLY: A-path computes h = relu(A*scale+shift) + res in registers (fuses the
// BN-apply+residual pass of the previous layer; bit-identical rounding points).

template<int K, int NN, bool BIAS, bool STATS, bool APPLY>
__global__ __launch_bounds__(256, 2) void gemm_stream(const u16* __restrict__ A,
                                                      const u16* __restrict__ Wt,
                                                      const float* __restrict__ bias,
                                                      const float* __restrict__ scale,
                                                      const float* __restrict__ shift,
                                                      const u16* __restrict__ res,
                                                      u16* __restrict__ C,
                                                      float* __restrict__ partial, int M) {
  constexpr int CPR = K / 8;           // 16B chunks per row of B
  __shared__ u16 Blds[128 * K];
  __shared__ float sstat[256];
  const int tid = threadIdx.x;
  const int lane = tid & 63;
  const int wid = tid >> 6;
  const int bn = blockIdx.y * 128;
  const int kh = lane >> 4;            // k-half-chunk 0..3

  if constexpr (STATS) { sstat[tid] = 0.f; }

  // stage B: 128 cols x K, swizzled source -> linear LDS
  const u16* Bsrc = Wt + (size_t)bn * K;
  #pragma unroll
  for (int i = 0; i < CPR / 2; ++i) {
    int flat = i * 256 + tid;
    int r = flat / CPR;
    int c = flat & (CPR - 1);
    __builtin_amdgcn_global_load_lds(
        (const __attribute__((address_space(1))) void*)(Bsrc + (size_t)r * K + (c ^ (r & 7)) * 8),
        (__attribute__((address_space(3))) void*)(&Blds[flat * 8]),
        16, 0, 0);
  }
  __syncthreads();

  float cs[8] = {}, cq[8] = {};
  const int nch = (M + 63) / 64;
  for (int ch = blockIdx.x * 4 + wid; ch < nch; ch += gridDim.x * 4) {
    const int r0 = ch * 64;
    // hoist A/res row pointers (clamped; garbage rows masked at store/stats)
    const u16* arow[4];
    const u16* rrow[4];
    #pragma unroll
    for (int rf = 0; rf < 4; ++rf) {
      int row = r0 + rf * 16 + (lane & 15);
      if (row >= M) row = M - 1;
      arow[rf] = A + (size_t)row * K + kh * 8;
      if constexpr (APPLY) rrow[rf] = res + (size_t)row * K + kh * 8;
    }
    f32x4 acc[4][8] = {};
    #pragma unroll
    for (int ks = 0; ks < K / 32; ++ks) {
      FragU a[4], b[8];
      if constexpr (APPLY) {
        const int c0 = ks * 32 + kh * 8;
        float sc[8], sh[8];
        *(float4*)sc       = *(const float4*)(scale + c0);
        *(float4*)(sc + 4) = *(const float4*)(scale + c0 + 4);
        *(float4*)sh       = *(const float4*)(shift + c0);
        *(float4*)(sh + 4) = *(const float4*)(shift + c0 + 4);
        #pragma unroll
        for (int rf = 0; rf < 4; ++rf) {
          uint4 araw = *(const uint4*)(arow[rf] + ks * 32);
          uint4 rraw = *(const uint4*)(rrow[rf] + ks * 32);
          const u16* ap = (const u16*)&araw;
          const u16* rp = (const u16*)&rraw;
          u16 o[8];
          #pragma unroll
          for (int j = 0; j < 8; ++j)
            o[j] = f2bf(fmaxf(fmaf(bf2f(ap[j]), sc[j], sh[j]), 0.f) + bf2f(rp[j]));
          a[rf].u = *(const uint4*)o;
        }
      } else {
        #pragma unroll
        for (int rf = 0; rf < 4; ++rf)
          a[rf].u = *(const uint4*)(arow[rf] + ks * 32);
      }
      #pragma unroll
      for (int cf = 0; cf < 8; ++cf) {
        int rr = cf * 16 + (lane & 15);
        int c = ks * 4 + kh;
        b[cf].u = *(const uint4*)(&Blds[rr * K + ((c ^ (rr & 7)) * 8)]);
      }
      #pragma unroll
      for (int rf = 0; rf < 4; ++rf)
        #pragma unroll
        for (int cf = 0; cf < 8; ++cf)
          acc[rf][cf] = __builtin_amdgcn_mfma_f32_16x16x32_bf16(a[rf].v, b[cf].v,
                                                                acc[rf][cf], 0, 0, 0);
    }
    // epilogue: C/D frag mapping col=lane&15, row=(lane>>4)*4+j
    #pragma unroll
    for (int cf = 0; cf < 8; ++cf) {
      int gc = bn + cf * 16 + (lane & 15);
      float bv = 0.f;
      if constexpr (BIAS) bv = bias[gc];
      #pragma unroll
      for (int rf = 0; rf < 4; ++rf) {
        int gr0 = r0 + rf * 16 + kh * 4;
        #pragma unroll
        for (int j = 0; j < 4; ++j) {
          int gr = gr0 + j;
          if (gr < M) {
            float v = acc[rf][cf][j] + bv;
            C[(size_t)gr * NN + gc] = f2bf(v);
            if constexpr (STATS) { cs[cf] += v; cq[cf] = fmaf(v, v, cq[cf]); }
          }
        }
      }
    }
  }

  if constexpr (STATS) {
    #pragma unroll
    for (int cf = 0; cf < 8; ++cf) {
      float s = cs[cf], q = cq[cf];
      s += __shfl_xor(s, 16, 64); q += __shfl_xor(q, 16, 64);
      s += __shfl_xor(s, 32, 64); q += __shfl_xor(q, 32, 64);
      if (kh == 0) {
        int cl = cf * 16 + (lane & 15);
        atomicAdd(&sstat[cl], s);
        atomicAdd(&sstat[128 + cl], q);
      }
    }
    __syncthreads();
    if (tid < 128) {
      size_t pb = ((size_t)blockIdx.y * gridDim.x + blockIdx.x) * 256;
      partial[pb + tid]       = sstat[tid];
      partial[pb + 128 + tid] = sstat[128 + tid];
    }
  }
}

// ---------------- BatchNorm stats / finalize / apply ----------------

template<int F>
__global__ __launch_bounds__(256) void stats_bf16(const u16* __restrict__ m, int n,
                                                  float* __restrict__ partial) {
  constexpr int COLS = F / 4;
  constexpr int RG = 256 / COLS;
  int c4 = threadIdx.x % COLS;
  int rg = threadIdx.x / COLS;
  float s[4] = {}, q[4] = {};
  for (int r = blockIdx.x * RG + rg; r < n; r += gridDim.x * RG) {
    u16 t[4];
    *(uint2*)t = *(const uint2*)(m + (size_t)r * F + c4 * 4);
    #pragma unroll
    for (int j = 0; j < 4; ++j) { float v = bf2f(t[j]); s[j] += v; q[j] = fmaf(v, v, q[j]); }
  }
  __shared__ float ls[256][8];
  #pragma unroll
  for (int j = 0; j < 4; ++j) { ls[threadIdx.x][j] = s[j]; ls[threadIdx.x][4 + j] = q[j]; }
  __syncthreads();
  if (rg == 0) {
    for (int g = 1; g < RG; ++g) {
      #pragma unroll
      for (int j = 0; j < 4; ++j) {
        s[j] += ls[g * COLS + c4][j];
        q[j] += ls[g * COLS + c4][4 + j];
      }
    }
    #pragma unroll
    for (int j = 0; j < 4; ++j) {
      partial[(size_t)blockIdx.x * 2 * F + c4 * 4 + j]     = s[j];
      partial[(size_t)blockIdx.x * 2 * F + F + c4 * 4 + j] = q[j];
    }
  }
}

// partials from gemm_stream<STATS>: [by*GX+bx][{sum[128],sumsq[128]}]
__global__ __launch_bounds__(64) void finalize_gemm(const float* __restrict__ partial, int GX, int n,
                                                    const float* __restrict__ g,
                                                    const float* __restrict__ be,
                                                    float* __restrict__ scale,
                                                    float* __restrict__ shift) {
  int c = blockIdx.x;
  int by = c >> 7, cl = c & 127;
  float s = 0.f, q = 0.f;
  for (int bx = threadIdx.x; bx < GX; bx += 64) {
    const float* pb = partial + ((size_t)by * GX + bx) * 256;
    s += pb[cl]; q += pb[128 + cl];
  }
  #pragma unroll
  for (int d = 32; d > 0; d >>= 1) { s += __shfl_down(s, d, 64); q += __shfl_down(q, d, 64); }
  if (threadIdx.x == 0) {
    float inv_n = 1.0f / (float)n;
    float mu = s * inv_n;
    float var = q * inv_n - mu * mu;
    float rs = rsqrtf(var + BN_EPS);
    float sc = rs * g[c];
    scale[c] = sc;
    shift[c] = fmaf(-mu, sc, be[c]);
  }
}

// partials from stats_bf16<256>: [b][{sum[256],sumsq[256]}]
__global__ __launch_bounds__(64) void finalize_agg(const float* __restrict__ partial, int nb, int n,
                                                   const float* __restrict__ g,
                                                   const float* __restrict__ be,
                                                   float* __restrict__ scale,
                                                   float* __restrict__ shift) {
  int c = blockIdx.x;
  float s = 0.f, q = 0.f;
  for (int b = threadIdx.x; b < nb; b += 64) {
    s += partial[(size_t)b * 512 + c];
    q += partial[(size_t)b * 512 + 256 + c];
  }
  #pragma unroll
  for (int d = 32; d > 0; d >>= 1) { s += __shfl_down(s, d, 64); q += __shfl_down(q, d, 64); }
  if (threadIdx.x == 0) {
    float inv_n = 1.0f / (float)n;
    float mu = s * inv_n;
    float var = q * inv_n - mu * mu;
    float rs = rsqrtf(var + BN_EPS);
    float sc = rs * g[c];
    scale[c] = sc;
    shift[c] = fmaf(-mu, sc, be[c]);
  }
}

template<int F, bool RES>
__global__ __launch_bounds__(256) void apply_bf16(const u16* __restrict__ m,
                                                  const float* __restrict__ scale,
                                                  const float* __restrict__ shift,
                                                  const u16* __restrict__ res,
                                                  u16* __restrict__ out, int n) {
  int i = blockIdx.x * 256 + threadIdx.x;  // group of 8 feats
  if (i >= n * (F / 8)) return;
  int c = i & (F / 8 - 1);
  u16 t[8];
  *(uint4*)t = *(const uint4*)(m + (size_t)i * 8);
  float sc[8], sh[8];
  *(float4*)sc       = ((const float4*)scale)[c * 2];
  *(float4*)(sc + 4) = ((const float4*)scale)[c * 2 + 1];
  *(float4*)sh       = ((const float4*)shift)[c * 2];
  *(float4*)(sh + 4) = ((const float4*)shift)[c * 2 + 1];
  float h[8];
  #pragma unroll
  for (int j = 0; j < 8; ++j) h[j] = fmaxf(fmaf(bf2f(t[j]), sc[j], sh[j]), 0.f);
  if constexpr (RES) {
    u16 r[8];
    *(uint4*)r = *(const uint4*)(res + (size_t)i * 8);
    #pragma unroll
    for (int j = 0; j < 8; ++j) h[j] += bf2f(r[j]);
  }
  u16 o[8];
  #pragma unroll
  for (int j = 0; j < 8; ++j) o[j] = f2bf(h[j]);
  *(uint4*)(out + (size_t)i * 8) = *(uint4*)o;
}

// ---------------- launcher ----------------

extern "C" void kernel_launch(void* const* d_in, const int* in_sizes, int n_in,
                              void* d_out, int out_size, void* d_ws, size_t ws_size,
                              hipStream_t stream) {
  const float* x   = (const float*)d_in[0];
  const int*   ei  = (const int*)d_in[1];   // int32 per harness dtype rule
  const float* W0  = (const float*)d_in[2];
  const float* b0  = (const float*)d_in[3];
  const float* g0  = (const float*)d_in[4];
  const float* be0 = (const float*)d_in[5];
  const float* W1  = (const float*)d_in[6];
  const float* b1  = (const float*)d_in[7];
  const float* g1  = (const float*)d_in[8];
  const float* be1 = (const float*)d_in[9];
  const float* W2  = (const float*)d_in[10];
  const float* b2  = (const float*)d_in[11];
  float* out = (float*)d_out;

  const int N = in_sizes[0] / D_IN;
  const int E = in_sizes[1] / 2;
  const int* esrc = ei;
  const int* edst = ei + E;

  char* p = (char*)d_ws;
  auto alloc = [&](size_t bytes) { char* r = p; p += (bytes + 255) & ~(size_t)255; return r; };
  int* cnt     = (int*)alloc((size_t)2 * N * 4);   // cnt + cursor contiguous
  int* cursor  = cnt + N;
  int* rowptr  = (int*)alloc(((size_t)N + 1) * 4);
  int* col     = (int*)alloc((size_t)E * 4);
  float* dinv  = (float*)alloc((size_t)N * 4);
  const int nb = (N + 1023) / 1024;
  int* bsum    = (int*)alloc((size_t)nb * 4);
  constexpr int SB = 128;
  const int GX = 196;
  float* partial = (float*)alloc((size_t)(SB > GX * 2 ? SB : GX * 2) * 512 * 4);
  float* scalev  = (float*)alloc(256 * 4);
  float* shiftv  = (float*)alloc(256 * 4);
  u16* Wt0 = (u16*)alloc((size_t)256 * 128 * 2);
  u16* Wt1 = (u16*)alloc((size_t)256 * 256 * 2);
  u16* Wt2 = (u16*)alloc((size_t)128 * 256 * 2);
  // activation slots (aliased by disjoint live ranges):
  u16* slotX  = (u16*)alloc((size_t)N * 128 * 2);  // x_bf (L0), then m2 (L2)
  u16* slotAM = (u16*)alloc((size_t)N * 256 * 2);  // a0 (L0), then m1 (L1)
  u16* slotMH = (u16*)alloc((size_t)N * 256 * 2);  // m0 -> h0 in-place
  u16* slotAH = (u16*)alloc((size_t)N * 256 * 2);  // a1 (h1 is fused into G3's A-path)
  u16* x_bf = slotX;  u16* m2 = slotX;
  u16* a0   = slotAM; u16* m1 = slotAM;
  u16* m0   = slotMH; u16* h0 = slotMH;
  u16* a1   = slotAH;
  (void)ws_size; (void)n_in; (void)out_size;

  // fused prep (zero + conversions) + graph preprocessing
  const int BZ = (2 * N + 255) / 256;
  const int BX = (N * 32 + 255) / 256;
  prep_kernel<<<BZ + BX + 512, 256, 0, stream>>>(cnt, 2 * N, BZ, x, x_bf,
                                                 W0, Wt0, W1, Wt1, W2, Wt2, N, BX);
  count_kernel<<<(E + 255) / 256, 256, 0, stream>>>(edst, E, cnt);
  scan_sum_kernel<<<nb, 1024, 0, stream>>>(cnt, N, bsum, dinv);
  scan_final_kernel<<<nb, 1024, 0, stream>>>(cnt, N, bsum, rowptr);
  fill_kernel<<<(E + 255) / 256, 256, 0, stream>>>(esrc, edst, E, rowptr, cursor, col);

  const int aggGrid = (N + 3) / 4;

  // layer 0: a0 = Agg(x); m0 = a0@W0 + b0 (stats fused); h0 = relu(bn(m0))
  agg_bf16<128, false, false><<<aggGrid, 256, 0, stream>>>(x_bf, rowptr, col, dinv,
                                                           nullptr, nullptr, a0, N);
  gemm_stream<128, 256, true, true, false><<<dim3(GX, 2), 256, 0, stream>>>(
      a0, Wt0, b0, nullptr, nullptr, nullptr, m0, partial, N);
  finalize_gemm<<<256, 64, 0, stream>>>(partial, GX, N, g0, be0, scalev, shiftv);
  apply_bf16<256, false><<<(N * 32 + 255) / 256, 256, 0, stream>>>(m0, scalev, shiftv,
                                                                   nullptr, h0, N);

  // layer 1: m1 = h0@W1; a1 = Agg(m1)+b1; stats(a1) -> scale/shift
  gemm_stream<256, 256, false, false, false><<<dim3(GX, 2), 256, 0, stream>>>(
      h0, Wt1, nullptr, nullptr, nullptr, nullptr, m1, nullptr, N);
  agg_bf16<256, true, false><<<aggGrid, 256, 0, stream>>>(m1, rowptr, col, dinv,
                                                          b1, nullptr, a1, N);
  stats_bf16<256><<<SB, 256, 0, stream>>>(a1, N, partial);
  finalize_agg<<<256, 64, 0, stream>>>(partial, SB, N, g1, be1, scalev, shiftv);

  // layer 2: m2 = (relu(bn1(a1)) + h0)@W2 (apply fused into A-path);
  //          out = Agg(m2) + b2 + x (x fp32 exact)
  gemm_stream<256, 128, false, false, true><<<dim3(GX, 1), 256, 0, stream>>>(
      a1, Wt2, nullptr, scalev, shiftv, h0, m2, nullptr, N);
  agg_bf16<128, true, true><<<aggGrid, 256, 0, stream>>>(m2, rowptr, col, dinv,
                                                         b2, x, out, N);
}

// Round 8
// 409.284 us; speedup vs baseline: 1.0530x; 1.0530x over previous
//
#include <hip/hip_runtime.h>

#define BN_EPS 1e-5f

static constexpr int D_IN = 128;

using u16 = unsigned short;
using f32x4  = __attribute__((ext_vector_type(4))) float;
using bf16x8 = __attribute__((ext_vector_type(8))) __bf16;

union FragU { uint4 u; bf16x8 v; };

__device__ __forceinline__ u16 f2bf(float f) {
  unsigned int u = __float_as_uint(f);
  u += 0x7FFFu + ((u >> 16) & 1u);   // RNE
  return (u16)(u >> 16);
}
__device__ __forceinline__ float bf2f(u16 h) {
  return __uint_as_float(((unsigned int)h) << 16);
}

// ---------------- graph preprocessing (int32 edge_index per harness rule) -----

__global__ __launch_bounds__(256) void count_kernel(const int* __restrict__ dst, int E,
                                                    int* __restrict__ cnt) {
  int e = blockIdx.x * 256 + threadIdx.x;
  if (e < E) atomicAdd(&cnt[dst[e]], 1);
}

// block sums for scan + dinv = rsqrt(deg+1) fused
__global__ __launch_bounds__(1024) void scan_sum_kernel(const int* __restrict__ cnt, int n,
                                                        int* __restrict__ bsum,
                                                        float* __restrict__ dinv) {
  __shared__ int sdata[1024];
  int i = blockIdx.x * 1024 + threadIdx.x;
  int v = (i < n) ? cnt[i] : 0;
  if (i < n) dinv[i] = rsqrtf((float)v + 1.0f);  // +1: self loop
  sdata[threadIdx.x] = v;
  __syncthreads();
  for (int s = 512; s > 0; s >>= 1) {
    if (threadIdx.x < s) sdata[threadIdx.x] += sdata[threadIdx.x + s];
    __syncthreads();
  }
  if (threadIdx.x == 0) bsum[blockIdx.x] = sdata[0];
}

// exclusive scan; per-block boff computed in-kernel from bsum (<=49 adds)
__global__ __launch_bounds__(1024) void scan_final_kernel(const int* __restrict__ cnt, int n,
                                                          const int* __restrict__ bsum,
                                                          int* __restrict__ rowptr) {
  __shared__ int wt[16];
  __shared__ int sboff;
  int i = blockIdx.x * 1024 + threadIdx.x;
  int lane = threadIdx.x & 63, w = threadIdx.x >> 6;
  int v = (i < n) ? cnt[i] : 0;
  int x = v;
  #pragma unroll
  for (int d = 1; d < 64; d <<= 1) {
    int t = __shfl_up(x, d, 64);
    if (lane >= d) x += t;
  }
  if (lane == 63) wt[w] = x;
  __syncthreads();
  if (threadIdx.x == 0) {
    int run = 0;
    #pragma unroll
    for (int k = 0; k < 16; ++k) { int t = wt[k]; wt[k] = run; run += t; }
    int bo = 0;
    for (int b = 0; b < blockIdx.x; ++b) bo += bsum[b];
    sboff = bo;
  }
  __syncthreads();
  if (i < n) {
    rowptr[i] = x - v + wt[w] + sboff;
    if (i == n - 1) rowptr[n] = x + wt[w] + sboff;  // total = E
  }
}

__global__ __launch_bounds__(256) void fill_kernel(const int* __restrict__ src,
                                                   const int* __restrict__ dst, int E,
                                                   const int* __restrict__ rowptr,
                                                   int* __restrict__ cursor, int* __restrict__ col) {
  int e = blockIdx.x * 256 + threadIdx.x;
  if (e < E) {
    int d = dst[e];
    int p = atomicAdd(&cursor[d], 1);
    col[rowptr[d] + p] = src[e];
  }
}

// -------- fused prep: zero cnt/cursor, x->bf16, W0/W1/W2 -> transposed bf16 ---

__global__ __launch_bounds__(256) void prep_kernel(int* __restrict__ zbuf, int nz, int BZ,
                                                   const float* __restrict__ x, u16* __restrict__ x_bf,
                                                   const float* __restrict__ W0, u16* __restrict__ Wt0,
                                                   const float* __restrict__ W1, u16* __restrict__ Wt1,
                                                   const float* __restrict__ W2, u16* __restrict__ Wt2,
                                                   int N, int BX) {
  int b = blockIdx.x, tid = threadIdx.x;
  if (b < BZ) {
    int i = b * 256 + tid;
    if (i < nz) zbuf[i] = 0;
  } else if (b < BZ + BX) {
    int i = (b - BZ) * 256 + tid;
    if (i < N * 32) {
      float4 v = ((const float4*)x)[i];
      u16 o[4] = { f2bf(v.x), f2bf(v.y), f2bf(v.z), f2bf(v.w) };
      ((uint2*)x_bf)[i] = *(uint2*)o;
    }
  } else if (b < BZ + BX + 128) {       // W0 [128][256] -> Wt0 [256][128]
    int idx = (b - BZ - BX) * 256 + tid;
    int k = idx >> 8, nc = idx & 255;
    Wt0[nc * 128 + k] = f2bf(W0[idx]);
  } else if (b < BZ + BX + 384) {       // W1 [256][256] -> Wt1 [256][256]
    int idx = (b - BZ - BX - 128) * 256 + tid;
    int k = idx >> 8, nc = idx & 255;
    Wt1[nc * 256 + k] = f2bf(W1[idx]);
  } else {                              // W2 [256][128] -> Wt2 [128][256]
    int idx = (b - BZ - BX - 384) * 256 + tid;
    int k = idx >> 7, nc = idx & 127;
    Wt2[nc * 256 + k] = f2bf(W2[idx]);
  }
}

// ---------------- aggregation over bf16 features ----------------
// out[i] = dinv[i]*(sum_j dinv[j]*in[j] + dinv[i]*in[i]) (+bias)(+x fp32 if FINAL)

template<int F, bool BIAS, bool FINAL>
__global__ __launch_bounds__(256) void agg_bf16(const u16* __restrict__ in,
                                                const int* __restrict__ rowptr,
                                                const int* __restrict__ col,
                                                const float* __restrict__ dinv,
                                                const float* __restrict__ bias,
                                                const float* __restrict__ xres,
                                                void* __restrict__ outv, int n) {
  constexpr int V = F / 64;  // bf16 elems per lane (2 or 4)
  int node = blockIdx.x * 4 + (threadIdx.x >> 6);
  if (node >= n) return;
  int lane = threadIdx.x & 63;
  const int off = lane * V;
  const size_t rowbase = (size_t)node * F + off;

  float di = dinv[node];
  float acc[V];
  {
    u16 t[V];
    if constexpr (V == 4) *(uint2*)t = *(const uint2*)(in + rowbase);
    else                  *(unsigned int*)t = *(const unsigned int*)(in + rowbase);
    #pragma unroll
    for (int j = 0; j < V; ++j) acc[j] = di * bf2f(t[j]);
  }

  int e   = __builtin_amdgcn_readfirstlane(rowptr[node]);
  int end = __builtin_amdgcn_readfirstlane(rowptr[node + 1]);
  for (; e + 4 <= end; e += 4) {
    int s0 = col[e], s1 = col[e + 1], s2 = col[e + 2], s3 = col[e + 3];
    float w0 = dinv[s0], w1 = dinv[s1], w2 = dinv[s2], w3 = dinv[s3];
    u16 t0[V], t1[V], t2[V], t3[V];
    if constexpr (V == 4) {
      *(uint2*)t0 = *(const uint2*)(in + (size_t)s0 * F + off);
      *(uint2*)t1 = *(const uint2*)(in + (size_t)s1 * F + off);
      *(uint2*)t2 = *(const uint2*)(in + (size_t)s2 * F + off);
      *(uint2*)t3 = *(const uint2*)(in + (size_t)s3 * F + off);
    } else {
      *(unsigned int*)t0 = *(const unsigned int*)(in + (size_t)s0 * F + off);
      *(unsigned int*)t1 = *(const unsigned int*)(in + (size_t)s1 * F + off);
      *(unsigned int*)t2 = *(const unsigned int*)(in + (size_t)s2 * F + off);
      *(unsigned int*)t3 = *(const unsigned int*)(in + (size_t)s3 * F + off);
    }
    #pragma unroll
    for (int j = 0; j < V; ++j) acc[j] = fmaf(w0, bf2f(t0[j]), acc[j]);
    #pragma unroll
    for (int j = 0; j < V; ++j) acc[j] = fmaf(w1, bf2f(t1[j]), acc[j]);
    #pragma unroll
    for (int j = 0; j < V; ++j) acc[j] = fmaf(w2, bf2f(t2[j]), acc[j]);
    #pragma unroll
    for (int j = 0; j < V; ++j) acc[j] = fmaf(w3, bf2f(t3[j]), acc[j]);
  }
  for (; e < end; ++e) {
    int s0 = col[e];
    float w0 = dinv[s0];
    u16 t0[V];
    if constexpr (V == 4) *(uint2*)t0 = *(const uint2*)(in + (size_t)s0 * F + off);
    else                  *(unsigned int*)t0 = *(const unsigned int*)(in + (size_t)s0 * F + off);
    #pragma unroll
    for (int j = 0; j < V; ++j) acc[j] = fmaf(w0, bf2f(t0[j]), acc[j]);
  }

  #pragma unroll
  for (int j = 0; j < V; ++j) acc[j] *= di;
  if constexpr (BIAS) {
    #pragma unroll
    for (int j = 0; j < V; ++j) acc[j] += bias[off + j];
  }
  if constexpr (FINAL) {
    float* out = (float*)outv;
    float xr[V];
    if constexpr (V == 2) *(float2*)xr = *(const float2*)(xres + rowbase);
    else                  *(float4*)xr = *(const float4*)(xres + rowbase);
    #pragma unroll
    for (int j = 0; j < V; ++j) acc[j] += xr[j];
    if constexpr (V == 2) *(float2*)(out + rowbase) = *(float2*)acc;
    else                  *(float4*)(out + rowbase) = *(float4*)acc;
  } else {
    u16* out = (u16*)outv;
    u16 o[V];
    #pragma unroll
    for (int j = 0; j < V; ++j) o[j] = f2bf(acc[j]);
    if constexpr (V == 4) *(uint2*)(out + rowbase) = *(uint2*)o;
    else                  *(unsigned int*)(out + rowbase) = *(unsigned int*)o;
  }
}

// ------- streaming MFMA GEMM: C[M,NN] = A[M,K] @ Wt[NN,K]^T (+bias) ----------
// B (one 128-col block of Wt) lives entirely in LDS (<=64KB), loaded once via
// global_load_lds with pre-swizzled source chunks (involution c^(r&7) on 16B
// chunks, linear LDS dest). ONE barrier; then each wave independently streams
// 64-row A chunks. No barriers in the main loop.
// STATS: per-block BN partials (padded rows masked) via shfl + LDS atomics.

template<int K, int NN, bool BIAS, bool STATS>
__global__ __launch_bounds__(256, 2) void gemm_stream(const u16* __restrict__ A,
                                                      const u16* __restrict__ Wt,
                                                      const float* __restrict__ bias,
                                                      u16* __restrict__ C,
                                                      float* __restrict__ partial, int M) {
  constexpr int CPR = K / 8;           // 16B chunks per row of B
  __shared__ u16 Blds[128 * K];
  __shared__ float sstat[256];
  const int tid = threadIdx.x;
  const int lane = tid & 63;
  const int wid = tid >> 6;
  const int bn = blockIdx.y * 128;
  const int kh = lane >> 4;            // k-half-chunk 0..3

  if constexpr (STATS) { sstat[tid] = 0.f; }

  // stage B: 128 cols x K, swizzled source -> linear LDS
  const u16* Bsrc = Wt + (size_t)bn * K;
  #pragma unroll
  for (int i = 0; i < CPR / 2; ++i) {
    int flat = i * 256 + tid;
    int r = flat / CPR;
    int c = flat & (CPR - 1);
    __builtin_amdgcn_global_load_lds(
        (const __attribute__((address_space(1))) void*)(Bsrc + (size_t)r * K + (c ^ (r & 7)) * 8),
        (__attribute__((address_space(3))) void*)(&Blds[flat * 8]),
        16, 0, 0);
  }
  __syncthreads();

  float cs[8] = {}, cq[8] = {};
  const int nch = (M + 63) / 64;
  for (int ch = blockIdx.x * 4 + wid; ch < nch; ch += gridDim.x * 4) {
    const int r0 = ch * 64;
    // hoist A row pointers (clamped; garbage rows masked at store/stats)
    const u16* arow[4];
    #pragma unroll
    for (int rf = 0; rf < 4; ++rf) {
      int row = r0 + rf * 16 + (lane & 15);
      if (row >= M) row = M - 1;
      arow[rf] = A + (size_t)row * K + kh * 8;
    }
    f32x4 acc[4][8] = {};
    #pragma unroll
    for (int ks = 0; ks < K / 32; ++ks) {
      FragU a[4], b[8];
      #pragma unroll
      for (int rf = 0; rf < 4; ++rf)
        a[rf].u = *(const uint4*)(arow[rf] + ks * 32);
      #pragma unroll
      for (int cf = 0; cf < 8; ++cf) {
        int rr = cf * 16 + (lane & 15);
        int c = ks * 4 + kh;
        b[cf].u = *(const uint4*)(&Blds[rr * K + ((c ^ (rr & 7)) * 8)]);
      }
      #pragma unroll
      for (int rf = 0; rf < 4; ++rf)
        #pragma unroll
        for (int cf = 0; cf < 8; ++cf)
          acc[rf][cf] = __builtin_amdgcn_mfma_f32_16x16x32_bf16(a[rf].v, b[cf].v,
                                                                acc[rf][cf], 0, 0, 0);
    }
    // epilogue: C/D frag mapping col=lane&15, row=(lane>>4)*4+j
    #pragma unroll
    for (int cf = 0; cf < 8; ++cf) {
      int gc = bn + cf * 16 + (lane & 15);
      float bv = 0.f;
      if constexpr (BIAS) bv = bias[gc];
      #pragma unroll
      for (int rf = 0; rf < 4; ++rf) {
        int gr0 = r0 + rf * 16 + kh * 4;
        #pragma unroll
        for (int j = 0; j < 4; ++j) {
          int gr = gr0 + j;
          if (gr < M) {
            float v = acc[rf][cf][j] + bv;
            C[(size_t)gr * NN + gc] = f2bf(v);
            if constexpr (STATS) { cs[cf] += v; cq[cf] = fmaf(v, v, cq[cf]); }
          }
        }
      }
    }
  }

  if constexpr (STATS) {
    #pragma unroll
    for (int cf = 0; cf < 8; ++cf) {
      float s = cs[cf], q = cq[cf];
      s += __shfl_xor(s, 16, 64); q += __shfl_xor(q, 16, 64);
      s += __shfl_xor(s, 32, 64); q += __shfl_xor(q, 32, 64);
      if (kh == 0) {
        int cl = cf * 16 + (lane & 15);
        atomicAdd(&sstat[cl], s);
        atomicAdd(&sstat[128 + cl], q);
      }
    }
    __syncthreads();
    if (tid < 128) {
      size_t pb = ((size_t)blockIdx.y * gridDim.x + blockIdx.x) * 256;
      partial[pb + tid]       = sstat[tid];
      partial[pb + 128 + tid] = sstat[128 + tid];
    }
  }
}

// ---------------- BatchNorm stats / finalize / apply ----------------

template<int F>
__global__ __launch_bounds__(256) void stats_bf16(const u16* __restrict__ m, int n,
                                                  float* __restrict__ partial) {
  constexpr int COLS = F / 4;
  constexpr int RG = 256 / COLS;
  int c4 = threadIdx.x % COLS;
  int rg = threadIdx.x / COLS;
  float s[4] = {}, q[4] = {};
  for (int r = blockIdx.x * RG + rg; r < n; r += gridDim.x * RG) {
    u16 t[4];
    *(uint2*)t = *(const uint2*)(m + (size_t)r * F + c4 * 4);
    #pragma unroll
    for (int j = 0; j < 4; ++j) { float v = bf2f(t[j]); s[j] += v; q[j] = fmaf(v, v, q[j]); }
  }
  __shared__ float ls[256][8];
  #pragma unroll
  for (int j = 0; j < 4; ++j) { ls[threadIdx.x][j] = s[j]; ls[threadIdx.x][4 + j] = q[j]; }
  __syncthreads();
  if (rg == 0) {
    for (int g = 1; g < RG; ++g) {
      #pragma unroll
      for (int j = 0; j < 4; ++j) {
        s[j] += ls[g * COLS + c4][j];
        q[j] += ls[g * COLS + c4][4 + j];
      }
    }
    #pragma unroll
    for (int j = 0; j < 4; ++j) {
      partial[(size_t)blockIdx.x * 2 * F + c4 * 4 + j]     = s[j];
      partial[(size_t)blockIdx.x * 2 * F + F + c4 * 4 + j] = q[j];
    }
  }
}

// partials from gemm_stream<STATS>: [by*GX+bx][{sum[128],sumsq[128]}]
__global__ __launch_bounds__(64) void finalize_gemm(const float* __restrict__ partial, int GX, int n,
                                                    const float* __restrict__ g,
                                                    const float* __restrict__ be,
                                                    float* __restrict__ scale,
                                                    float* __restrict__ shift) {
  int c = blockIdx.x;
  int by = c >> 7, cl = c & 127;
  float s = 0.f, q = 0.f;
  for (int bx = threadIdx.x; bx < GX; bx += 64) {
    const float* pb = partial + ((size_t)by * GX + bx) * 256;
    s += pb[cl]; q += pb[128 + cl];
  }
  #pragma unroll
  for (int d = 32; d > 0; d >>= 1) { s += __shfl_down(s, d, 64); q += __shfl_down(q, d, 64); }
  if (threadIdx.x == 0) {
    float inv_n = 1.0f / (float)n;
    float mu = s * inv_n;
    float var = q * inv_n - mu * mu;
    float rs = rsqrtf(var + BN_EPS);
    float sc = rs * g[c];
    scale[c] = sc;
    shift[c] = fmaf(-mu, sc, be[c]);
  }
}

// partials from stats_bf16<256>: [b][{sum[256],sumsq[256]}]
__global__ __launch_bounds__(64) void finalize_agg(const float* __restrict__ partial, int nb, int n,
                                                   const float* __restrict__ g,
                                                   const float* __restrict__ be,
                                                   float* __restrict__ scale,
                                                   float* __restrict__ shift) {
  int c = blockIdx.x;
  float s = 0.f, q = 0.f;
  for (int b = threadIdx.x; b < nb; b += 64) {
    s += partial[(size_t)b * 512 + c];
    q += partial[(size_t)b * 512 + 256 + c];
  }
  #pragma unroll
  for (int d = 32; d > 0; d >>= 1) { s += __shfl_down(s, d, 64); q += __shfl_down(q, d, 64); }
  if (threadIdx.x == 0) {
    float inv_n = 1.0f / (float)n;
    float mu = s * inv_n;
    float var = q * inv_n - mu * mu;
    float rs = rsqrtf(var + BN_EPS);
    float sc = rs * g[c];
    scale[c] = sc;
    shift[c] = fmaf(-mu, sc, be[c]);
  }
}

template<int F, bool RES>
__global__ __launch_bounds__(256) void apply_bf16(const u16* __restrict__ m,
                                                  const float* __restrict__ scale,
                                                  const float* __restrict__ shift,
                                                  const u16* __restrict__ res,
                                                  u16* __restrict__ out, int n) {
  int i = blockIdx.x * 256 + threadIdx.x;  // group of 8 feats
  if (i >= n * (F / 8)) return;
  int c = i & (F / 8 - 1);
  u16 t[8];
  *(uint4*)t = *(const uint4*)(m + (size_t)i * 8);
  float sc[8], sh[8];
  *(float4*)sc       = ((const float4*)scale)[c * 2];
  *(float4*)(sc + 4) = ((const float4*)scale)[c * 2 + 1];
  *(float4*)sh       = ((const float4*)shift)[c * 2];
  *(float4*)(sh + 4) = ((const float4*)shift)[c * 2 + 1];
  float h[8];
  #pragma unroll
  for (int j = 0; j < 8; ++j) h[j] = fmaxf(fmaf(bf2f(t[j]), sc[j], sh[j]), 0.f);
  if constexpr (RES) {
    u16 r[8];
    *(uint4*)r = *(const uint4*)(res + (size_t)i * 8);
    #pragma unroll
    for (int j = 0; j < 8; ++j) h[j] += bf2f(r[j]);
  }
  u16 o[8];
  #pragma unroll
  for (int j = 0; j < 8; ++j) o[j] = f2bf(h[j]);
  *(uint4*)(out + (size_t)i * 8) = *(uint4*)o;
}

// ---------------- launcher ----------------

extern "C" void kernel_launch(void* const* d_in, const int* in_sizes, int n_in,
                              void* d_out, int out_size, void* d_ws, size_t ws_size,
                              hipStream_t stream) {
  const float* x   = (const float*)d_in[0];
  const int*   ei  = (const int*)d_in[1];   // int32 per harness dtype rule
  const float* W0  = (const float*)d_in[2];
  const float* b0  = (const float*)d_in[3];
  const float* g0  = (const float*)d_in[4];
  const float* be0 = (const float*)d_in[5];
  const float* W1  = (const float*)d_in[6];
  const float* b1  = (const float*)d_in[7];
  const float* g1  = (const float*)d_in[8];
  const float* be1 = (const float*)d_in[9];
  const float* W2  = (const float*)d_in[10];
  const float* b2  = (const float*)d_in[11];
  float* out = (float*)d_out;

  const int N = in_sizes[0] / D_IN;
  const int E = in_sizes[1] / 2;
  const int* esrc = ei;
  const int* edst = ei + E;

  char* p = (char*)d_ws;
  auto alloc = [&](size_t bytes) { char* r = p; p += (bytes + 255) & ~(size_t)255; return r; };
  int* cnt     = (int*)alloc((size_t)2 * N * 4);   // cnt + cursor contiguous
  int* cursor  = cnt + N;
  int* rowptr  = (int*)alloc(((size_t)N + 1) * 4);
  int* col     = (int*)alloc((size_t)E * 4);
  float* dinv  = (float*)alloc((size_t)N * 4);
  const int nb = (N + 1023) / 1024;
  int* bsum    = (int*)alloc((size_t)nb * 4);
  constexpr int SB = 128;
  const int GX = 196;
  float* partial = (float*)alloc((size_t)(SB > GX * 2 ? SB : GX * 2) * 512 * 4);
  float* scalev  = (float*)alloc(256 * 4);
  float* shiftv  = (float*)alloc(256 * 4);
  u16* Wt0 = (u16*)alloc((size_t)256 * 128 * 2);
  u16* Wt1 = (u16*)alloc((size_t)256 * 256 * 2);
  u16* Wt2 = (u16*)alloc((size_t)128 * 256 * 2);
  // activation slots (aliased by disjoint live ranges):
  u16* slotX  = (u16*)alloc((size_t)N * 128 * 2);  // x_bf (L0), then m2 (L2)
  u16* slotAM = (u16*)alloc((size_t)N * 256 * 2);  // a0 (L0), then m1 (L1)
  u16* slotMH = (u16*)alloc((size_t)N * 256 * 2);  // m0 -> h0 in-place
  u16* slotAH = (u16*)alloc((size_t)N * 256 * 2);  // a1 -> h1 in-place
  u16* x_bf = slotX;  u16* m2 = slotX;
  u16* a0   = slotAM; u16* m1 = slotAM;
  u16* m0   = slotMH; u16* h0 = slotMH;
  u16* a1   = slotAH; u16* h1 = slotAH;
  (void)ws_size; (void)n_in; (void)out_size;

  // fused prep (zero + conversions) + graph preprocessing
  const int BZ = (2 * N + 255) / 256;
  const int BX = (N * 32 + 255) / 256;
  prep_kernel<<<BZ + BX + 512, 256, 0, stream>>>(cnt, 2 * N, BZ, x, x_bf,
                                                 W0, Wt0, W1, Wt1, W2, Wt2, N, BX);
  count_kernel<<<(E + 255) / 256, 256, 0, stream>>>(edst, E, cnt);
  scan_sum_kernel<<<nb, 1024, 0, stream>>>(cnt, N, bsum, dinv);
  scan_final_kernel<<<nb, 1024, 0, stream>>>(cnt, N, bsum, rowptr);
  fill_kernel<<<(E + 255) / 256, 256, 0, stream>>>(esrc, edst, E, rowptr, cursor, col);

  const int aggGrid = (N + 3) / 4;

  // layer 0: a0 = Agg(x); m0 = a0@W0 + b0 (stats fused); h0 = relu(bn(m0))
  agg_bf16<128, false, false><<<aggGrid, 256, 0, stream>>>(x_bf, rowptr, col, dinv,
                                                           nullptr, nullptr, a0, N);
  gemm_stream<128, 256, true, true><<<dim3(GX, 2), 256, 0, stream>>>(a0, Wt0, b0, m0, partial, N);
  finalize_gemm<<<256, 64, 0, stream>>>(partial, GX, N, g0, be0, scalev, shiftv);
  apply_bf16<256, false><<<(N * 32 + 255) / 256, 256, 0, stream>>>(m0, scalev, shiftv,
                                                                   nullptr, h0, N);

  // layer 1: m1 = h0@W1; a1 = Agg(m1)+b1; h1 = relu(bn(a1)) + h0
  gemm_stream<256, 256, false, false><<<dim3(GX, 2), 256, 0, stream>>>(h0, Wt1, nullptr, m1,
                                                                       nullptr, N);
  agg_bf16<256, true, false><<<aggGrid, 256, 0, stream>>>(m1, rowptr, col, dinv,
                                                          b1, nullptr, a1, N);
  stats_bf16<256><<<SB, 256, 0, stream>>>(a1, N, partial);
  finalize_agg<<<256, 64, 0, stream>>>(partial, SB, N, g1, be1, scalev, shiftv);
  apply_bf16<256, true><<<(N * 32 + 255) / 256, 256, 0, stream>>>(a1, scalev, shiftv,
                                                                  h0, h1, N);

  // layer 2: m2 = h1@W2; out = Agg(m2) + b2 + x (x fp32 exact)
  gemm_stream<256, 128, false, false><<<dim3(GX, 1), 256, 0, stream>>>(h1, Wt2, nullptr, m2,
                                                                       nullptr, N);
  agg_bf16<128, true, true><<<aggGrid, 256, 0, stream>>>(m2, rowptr, col, dinv,
                                                         b2, x, out, N);
}